// Round 1
// baseline (143.657 us; speedup 1.0000x reference)
//
#include <hip/hip_runtime.h>
#include <math.h>

// LDE: B=8, T=2048, D=64, F=128.
// out[b,d,f] = sum_t w[b,t,d] * (x[b,t,f] - dic[d,f]),
// w = softmax_T( -||x-dic|| * log_softmax(wei)[d] ), renormalized over T.
//
// One block per (b,d). Pass 1: dis -> logits into LDS. Block softmax stats.
// Pass 2: accumulate sum_t e_t * x[t,f]; epilogue subtracts S*dic and scales 1/S.

constexpr int Bn = 8, Tn = 2048, Dn = 64, Fn = 128;
constexpr int BLK = 512;           // 8 waves
constexpr int NHALF = BLK / 32;    // 16 half-waves; each half-wave covers all 128 f via float4

__global__ __launch_bounds__(BLK, 4) void lde_kernel(
    const float* __restrict__ x,    // (B,T,F)
    const float* __restrict__ dic,  // (D,F)
    const float* __restrict__ wei,  // (D,)
    float* __restrict__ out)        // (B, D*F)
{
    // b in low bits: round-robin workgroup->XCD dispatch keeps x[b] hot in one XCD's L2
    const int b = blockIdx.x & (Bn - 1);
    const int d = blockIdx.x >> 3;

    __shared__ float s_w[Tn];             // logits, then e_t = exp(logit - M)   (8 KB)
    __shared__ float s_red[BLK / 64];     // per-wave reduction scratch
    __shared__ float s_acc[NHALF][Fn];    // pass-2 partial accumulators         (8 KB)

    const int tid  = threadIdx.x;
    const int half = tid >> 5;            // half-wave id, 0..15
    const int l32  = tid & 31;
    const int f0   = l32 * 4;             // this lane's float4 feature offset

    // ---- log_softmax(wei)[d], computed redundantly per wave (D=64 = wave width) ----
    float wv = wei[tid & 63];
    float wmax = wv;
    #pragma unroll
    for (int m = 32; m >= 1; m >>= 1) wmax = fmaxf(wmax, __shfl_xor(wmax, m));
    float wsum = expf(wv - wmax);
    #pragma unroll
    for (int m = 32; m >= 1; m >>= 1) wsum += __shfl_xor(wsum, m);
    const float lsm = wei[d] - (wmax + logf(wsum));   // log_softmax(wei)[d]

    const float4 dic4 = *reinterpret_cast<const float4*>(dic + d * Fn + f0);
    const float* xb = x + (size_t)b * Tn * Fn;

    // ---- pass 1: logits[t] = -||x[t]-dic[d]|| * lsm ----
    for (int t = half; t < Tn; t += NHALF) {
        float4 xv = *reinterpret_cast<const float4*>(xb + t * Fn + f0);
        float rx = xv.x - dic4.x, ry = xv.y - dic4.y;
        float rz = xv.z - dic4.z, rw = xv.w - dic4.w;
        float p = rx * rx + ry * ry + rz * rz + rw * rw;
        #pragma unroll
        for (int m = 16; m >= 1; m >>= 1) p += __shfl_xor(p, m);  // butterfly within 32-lane half
        if (l32 == 0) s_w[t] = -sqrtf(p) * lsm;
    }
    __syncthreads();

    // ---- block max over T ----
    float lm = -INFINITY;
    for (int i = tid; i < Tn; i += BLK) lm = fmaxf(lm, s_w[i]);
    #pragma unroll
    for (int m = 32; m >= 1; m >>= 1) lm = fmaxf(lm, __shfl_xor(lm, m));
    if ((tid & 63) == 0) s_red[tid >> 6] = lm;
    __syncthreads();
    float M = -INFINITY;
    #pragma unroll
    for (int i = 0; i < BLK / 64; ++i) M = fmaxf(M, s_red[i]);

    // ---- exp + block sum; s_w[t] <- e_t ----
    float ls = 0.f;
    for (int i = tid; i < Tn; i += BLK) {
        float e = expf(s_w[i] - M);
        s_w[i] = e;
        ls += e;
    }
    #pragma unroll
    for (int m = 32; m >= 1; m >>= 1) ls += __shfl_xor(ls, m);
    __syncthreads();                       // everyone done reading s_red (M) and writing s_w
    if ((tid & 63) == 0) s_red[tid >> 6] = ls;
    __syncthreads();
    float S = 0.f;
    #pragma unroll
    for (int i = 0; i < BLK / 64; ++i) S += s_red[i];
    const float inv = 1.0f / S;            // softmax sum over T == 1; +1e-9 is sub-ulp in fp32

    // ---- pass 2: A_f = sum_t e_t * x[t,f] (per half-wave partial) ----
    float ax = 0.f, ay = 0.f, az = 0.f, aw = 0.f;
    for (int t = half; t < Tn; t += NHALF) {
        float e = s_w[t];                  // LDS broadcast (same addr across half-wave)
        float4 xv = *reinterpret_cast<const float4*>(xb + t * Fn + f0);
        ax += e * xv.x; ay += e * xv.y; az += e * xv.z; aw += e * xv.w;
    }
    *reinterpret_cast<float4*>(&s_acc[half][f0]) = make_float4(ax, ay, az, aw);
    __syncthreads();

    // ---- combine partials + epilogue: out = (A - S*dic) / S ----
    if (tid < Fn) {
        float a = 0.f;
        #pragma unroll
        for (int g = 0; g < NHALF; ++g) a += s_acc[g][tid];
        float dv = dic[d * Fn + tid];
        out[((size_t)b * Dn + d) * Fn + tid] = (a - S * dv) * inv;
    }
}

extern "C" void kernel_launch(void* const* d_in, const int* in_sizes, int n_in,
                              void* d_out, int out_size, void* d_ws, size_t ws_size,
                              hipStream_t stream) {
    const float* x   = (const float*)d_in[0];
    const float* dic = (const float*)d_in[1];
    const float* wei = (const float*)d_in[2];
    float* out = (float*)d_out;
    hipLaunchKernelGGL(lde_kernel, dim3(Bn * Dn), dim3(BLK), 0, stream,
                       x, dic, wei, out);
}

// Round 2
// 114.610 us; speedup vs baseline: 1.2534x; 1.2534x over previous
//
#include <hip/hip_runtime.h>
#include <math.h>

// LDE: B=8, T=2048, D=64, F=128.
// out[b,d,f] = sum_t w[b,t,d]*(x[b,t,f]-dic[d,f]),
// w = softmax_T( -||x-dic|| * log_softmax(wei)[d] ), renorm over T (no-op in fp32).
//
// R2: T split into NC=4 chunks (flash-style) to lift grid from 512 -> 2048
// blocks (occupancy was grid-capped at 44%). Kernel A computes per-chunk
// softmax stats + accumulator; kernel B merges chunks and writes out.

constexpr int Bn = 8, Tn = 2048, Dn = 64, Fn = 128;
constexpr int NC = 4;              // t-chunks per (b,d)
constexpr int Tc = Tn / NC;        // 512
constexpr int BLK = 512;           // 8 waves
constexpr int NHALF = BLK / 32;    // 16 half-waves
constexpr int WSTRIDE = Fn + 2;    // per-(b,d,c) record: A[128], M, S

__global__ __launch_bounds__(BLK) void lde_partial(
    const float* __restrict__ x,    // (B,T,F)
    const float* __restrict__ dic,  // (D,F)
    const float* __restrict__ wei,  // (D,)
    float* __restrict__ ws)         // (B*D*NC) records of WSTRIDE floats
{
    const int b = blockIdx.x & (Bn - 1);          // low bits -> XCD affinity for x[b]
    const int c = (blockIdx.x >> 3) & (NC - 1);
    const int d = blockIdx.x >> 5;

    __shared__ float s_w[Tc];              // chunk logits, then e_t        (2 KB)
    __shared__ float s_red[BLK / 64];
    __shared__ float s_acc[NHALF][Fn];     // pass-2 partials               (8 KB)

    const int tid  = threadIdx.x;
    const int half = tid >> 5;
    const int l32  = tid & 31;
    const int f0   = l32 * 4;

    // log_softmax(wei)[d] (redundant per wave; D=64 = wave width)
    float wv = wei[tid & 63];
    float wmax = wv;
    #pragma unroll
    for (int m = 32; m >= 1; m >>= 1) wmax = fmaxf(wmax, __shfl_xor(wmax, m));
    float wsum = expf(wv - wmax);
    #pragma unroll
    for (int m = 32; m >= 1; m >>= 1) wsum += __shfl_xor(wsum, m);
    const float lsm = wei[d] - (wmax + logf(wsum));

    const float4 dic4 = *reinterpret_cast<const float4*>(dic + d * Fn + f0);
    const float* xb = x + ((size_t)b * Tn + (size_t)c * Tc) * Fn;

    // ---- pass 1: chunk logits ----
    for (int t = half; t < Tc; t += NHALF) {
        float4 xv = *reinterpret_cast<const float4*>(xb + t * Fn + f0);
        float rx = xv.x - dic4.x, ry = xv.y - dic4.y;
        float rz = xv.z - dic4.z, rw = xv.w - dic4.w;
        float p = rx * rx + ry * ry + rz * rz + rw * rw;
        #pragma unroll
        for (int m = 16; m >= 1; m >>= 1) p += __shfl_xor(p, m);
        if (l32 == 0) s_w[t] = -sqrtf(p) * lsm;
    }
    __syncthreads();

    // ---- chunk max (Tc == BLK: one element per thread) ----
    float lm = s_w[tid];
    #pragma unroll
    for (int m = 32; m >= 1; m >>= 1) lm = fmaxf(lm, __shfl_xor(lm, m));
    if ((tid & 63) == 0) s_red[tid >> 6] = lm;
    __syncthreads();
    float M = -INFINITY;
    #pragma unroll
    for (int i = 0; i < BLK / 64; ++i) M = fmaxf(M, s_red[i]);

    // ---- exp + chunk sum ----
    float e = expf(s_w[tid] - M);
    s_w[tid] = e;
    float ls = e;
    #pragma unroll
    for (int m = 32; m >= 1; m >>= 1) ls += __shfl_xor(ls, m);
    __syncthreads();                       // s_red(max) reads + s_w writes drained
    if ((tid & 63) == 0) s_red[tid >> 6] = ls;
    __syncthreads();
    float S = 0.f;
    #pragma unroll
    for (int i = 0; i < BLK / 64; ++i) S += s_red[i];

    // ---- pass 2: A_c[f] = sum_t e_t * x[t,f] ----
    float ax = 0.f, ay = 0.f, az = 0.f, aw = 0.f;
    for (int t = half; t < Tc; t += NHALF) {
        float ev = s_w[t];                 // LDS broadcast
        float4 xv = *reinterpret_cast<const float4*>(xb + t * Fn + f0);
        ax += ev * xv.x; ay += ev * xv.y; az += ev * xv.z; aw += ev * xv.w;
    }
    *reinterpret_cast<float4*>(&s_acc[half][f0]) = make_float4(ax, ay, az, aw);
    __syncthreads();

    // ---- write chunk record ----
    float* rec = ws + ((size_t)((b * Dn + d) * NC + c)) * WSTRIDE;
    if (tid < Fn) {
        float a = 0.f;
        #pragma unroll
        for (int g = 0; g < NHALF; ++g) a += s_acc[g][tid];
        rec[tid] = a;
    }
    if (tid == 0) { rec[Fn] = M; rec[Fn + 1] = S; }
}

__global__ __launch_bounds__(Fn) void lde_combine(
    const float* __restrict__ ws,
    const float* __restrict__ dic,
    float* __restrict__ out)
{
    const int b = blockIdx.x & (Bn - 1);
    const int d = blockIdx.x >> 3;
    const int tid = threadIdx.x;           // 0..127 = f

    const float* base = ws + ((size_t)(b * Dn + d) * NC) * WSTRIDE;

    float Mc[NC], Sc[NC];
    #pragma unroll
    for (int c = 0; c < NC; ++c) {
        Mc[c] = base[c * WSTRIDE + Fn];
        Sc[c] = base[c * WSTRIDE + Fn + 1];
    }
    float M = Mc[0];
    #pragma unroll
    for (int c = 1; c < NC; ++c) M = fmaxf(M, Mc[c]);
    float S = 0.f, A = 0.f;
    #pragma unroll
    for (int c = 0; c < NC; ++c) {
        float wf = expf(Mc[c] - M);
        S += Sc[c] * wf;
        A += base[c * WSTRIDE + tid] * wf;
    }
    out[((size_t)b * Dn + d) * Fn + tid] = (A - S * dic[d * Fn + tid]) / S;
}

extern "C" void kernel_launch(void* const* d_in, const int* in_sizes, int n_in,
                              void* d_out, int out_size, void* d_ws, size_t ws_size,
                              hipStream_t stream) {
    const float* x   = (const float*)d_in[0];
    const float* dic = (const float*)d_in[1];
    const float* wei = (const float*)d_in[2];
    float* out = (float*)d_out;
    float* ws  = (float*)d_ws;             // needs B*D*NC*WSTRIDE*4 = 1.06 MB

    hipLaunchKernelGGL(lde_partial, dim3(Bn * Dn * NC), dim3(BLK), 0, stream,
                       x, dic, wei, ws);
    hipLaunchKernelGGL(lde_combine, dim3(Bn * Dn), dim3(Fn), 0, stream,
                       ws, dic, out);
}

// Round 3
// 86.282 us; speedup vs baseline: 1.6650x; 1.3283x over previous
//
#include <hip/hip_runtime.h>
#include <math.h>

// LDE via MFMA: dis^2 = ||x||^2 - 2*(x . dic) + ||dic||^2.
// GEMM1 (x.dicT) and GEMM2 (e^T.x) on mfma_f32_16x16x32_bf16 with bf16
// hi/lo split (3 products) for the cross term; norms in exact fp32.
// Block = 4 waves: Tc=64 t-chunk x DG=32 d-group. Flash-combine over chunks.

constexpr int Bn = 8, Tn = 2048, Dn = 64, Fn = 128;
constexpr int Tc = 64;              // t per block
constexpr int DG = 32;              // d per block
constexpr int NCH = Tn / Tc;        // 32 chunks
constexpr int NDG = Dn / DG;        // 2 d-groups
constexpr int XS = 136;             // xs row stride (halfwords): 128 + 8 pad
constexpr int XT = 72;              // xsT row stride: 64 + 8
constexpr int ESS = 72;             // es row stride
constexpr int RECF = DG * Fn + 2 * DG;  // record: A[32][128], M[32], S[32] = 4160 floats

typedef short short8 __attribute__((ext_vector_type(8)));
typedef float f32x4 __attribute__((ext_vector_type(4)));

__device__ inline unsigned short f2bf(float v) {          // RNE float->bf16
    union { float f; unsigned u; } c; c.f = v;
    return (unsigned short)((c.u + 0x7FFF + ((c.u >> 16) & 1)) >> 16);
}
__device__ inline float bf2f(unsigned short h) {
    union { unsigned u; float f; } c; c.u = ((unsigned)h) << 16;
    return c.f;
}

__global__ __launch_bounds__(256) void lde_mfma(
    const float* __restrict__ x, const float* __restrict__ dic,
    const float* __restrict__ wei, float* __restrict__ ws)
{
    const int b  = blockIdx.x & 7;                 // low bits -> XCD affinity
    const int dg = (blockIdx.x >> 3) & (NDG - 1);
    const int tc = blockIdx.x >> 4;
    const int t0 = tc * Tc;
    const int d0 = dg * DG;

    __shared__ unsigned short xs_hi[Tc * XS];      // x bf16 hi, [t][f]
    __shared__ unsigned short xs_lo[Tc * XS];      // x bf16 lo, [t][f]
    __shared__ unsigned short xsT[Fn * XT];        // x bf16 hi, [f][t] (GEMM2 B)
    __shared__ unsigned short es[DG * ESS];        // e bf16, [d][t]   (GEMM2 A)
    __shared__ float sq[Tc], sp[DG];
    __shared__ float wstat[4][DG], wsum[4][DG];
    __shared__ float sLSE;

    const int tid  = threadIdx.x;
    const int w    = tid >> 6;                     // wave 0..3
    const int lane = tid & 63;
    const int l15  = lane & 15;
    const int quad = lane >> 4;

    // ---- stage x: fp32 -> bf16 hi/lo into LDS; sq[t] = ||x_t||^2 exact ----
    {
        const float4* xb4 = (const float4*)(x + ((size_t)b * Tn + t0) * Fn);
        #pragma unroll
        for (int i = 0; i < 8; ++i) {
            int id4 = i * 256 + tid;               // coalesced float4 index
            int t = id4 >> 5, f4 = id4 & 31;
            float4 v = xb4[id4];
            unsigned short h0 = f2bf(v.x), h1 = f2bf(v.y),
                           h2 = f2bf(v.z), h3 = f2bf(v.w);
            unsigned short e0 = f2bf(v.x - bf2f(h0)), e1 = f2bf(v.y - bf2f(h1)),
                           e2 = f2bf(v.z - bf2f(h2)), e3 = f2bf(v.w - bf2f(h3));
            *(ushort4*)&xs_hi[t * XS + f4 * 4] = make_ushort4(h0, h1, h2, h3);
            *(ushort4*)&xs_lo[t * XS + f4 * 4] = make_ushort4(e0, e1, e2, e3);
            float q = v.x * v.x + v.y * v.y + v.z * v.z + v.w * v.w;
            #pragma unroll
            for (int m = 16; m >= 1; m >>= 1) q += __shfl_xor(q, m);  // 32-lane group
            if ((tid & 31) == 0) sq[t] = q;        // group shares t
        }
    }
    // ---- sp[d] = ||dic_d||^2 exact (8 threads per d) ----
    {
        int dl = tid >> 3, f16 = (tid & 7) * 16;
        const float4* dp = (const float4*)(dic + (size_t)(d0 + dl) * Fn + f16);
        float p = 0.f;
        #pragma unroll
        for (int i = 0; i < 4; ++i) {
            float4 v = dp[i];
            p += v.x * v.x + v.y * v.y + v.z * v.z + v.w * v.w;
        }
        #pragma unroll
        for (int m = 4; m >= 1; m >>= 1) p += __shfl_xor(p, m);
        if ((tid & 7) == 0) sp[dl] = p;
    }
    // ---- logsumexp(wei) (wave 0) ----
    if (tid < 64) {
        float wv = wei[tid];
        float m = wv;
        #pragma unroll
        for (int k = 32; k >= 1; k >>= 1) m = fmaxf(m, __shfl_xor(m, k));
        float e = expf(wv - m), s = e;
        #pragma unroll
        for (int k = 32; k >= 1; k >>= 1) s += __shfl_xor(s, k);
        if (tid == 0) sLSE = m + logf(s);
    }
    __syncthreads();

    // ---- build xsT[f][t] (hi only) from xs_hi ----
    {
        int f = tid & 127, th = (tid >> 7) * 32;   // each thread: one f, 32 t's
        #pragma unroll
        for (int g = 0; g < 8; ++g) {
            int tt = th + g * 4;
            unsigned short a0 = xs_hi[(tt + 0) * XS + f];
            unsigned short a1 = xs_hi[(tt + 1) * XS + f];
            unsigned short a2 = xs_hi[(tt + 2) * XS + f];
            unsigned short a3 = xs_hi[(tt + 3) * XS + f];
            *(ushort4*)&xsT[f * XT + tt] = make_ushort4(a0, a1, a2, a3);
        }
    }
    __syncthreads();

    // ---- GEMM1: S[t][d] = sum_f x[t,f]*dic[d,f]; wave w owns t-slab w*16 ----
    f32x4 acc1[2] = {{0.f, 0.f, 0.f, 0.f}, {0.f, 0.f, 0.f, 0.f}};
    const int tA = w * 16 + l15;                   // A-frag row (local t)
    #pragma unroll
    for (int k = 0; k < 4; ++k) {                  // K = 128 = 4 x 32
        short8 ahi = *(const short8*)&xs_hi[tA * XS + k * 32 + quad * 8];
        short8 alo = *(const short8*)&xs_lo[tA * XS + k * 32 + quad * 8];
        #pragma unroll
        for (int nt = 0; nt < 2; ++nt) {           // 2 n-tiles of 16 d
            int dd = d0 + nt * 16 + l15;
            const float4* bp = (const float4*)(dic + (size_t)dd * Fn + k * 32 + quad * 8);
            float4 v0 = bp[0], v1 = bp[1];
            float vv[8] = {v0.x, v0.y, v0.z, v0.w, v1.x, v1.y, v1.z, v1.w};
            short8 bhi, blo;
            #pragma unroll
            for (int j = 0; j < 8; ++j) {
                unsigned short h = f2bf(vv[j]);
                bhi[j] = (short)h;
                blo[j] = (short)f2bf(vv[j] - bf2f(h));
            }
            acc1[nt] = __builtin_amdgcn_mfma_f32_16x16x32_bf16(ahi, bhi, acc1[nt], 0, 0, 0);
            acc1[nt] = __builtin_amdgcn_mfma_f32_16x16x32_bf16(alo, bhi, acc1[nt], 0, 0, 0);
            acc1[nt] = __builtin_amdgcn_mfma_f32_16x16x32_bf16(ahi, blo, acc1[nt], 0, 0, 0);
        }
    }

    // ---- logits + chunk softmax stats (per d over the block's 64 t) ----
    // D layout: n(col)=l15 -> d, m(row)=quad*4+r -> t within slab
    const float lse = sLSE;
    float logit[2][4], Mc[2], Sc[2], eloc[2][4];
    #pragma unroll
    for (int nt = 0; nt < 2; ++nt) {
        float lsm = wei[d0 + nt * 16 + l15] - lse;
        #pragma unroll
        for (int r = 0; r < 4; ++r) {
            int tt = w * 16 + quad * 4 + r;
            float s2 = sq[tt] - 2.f * acc1[nt][r] + sp[nt * 16 + l15];
            logit[nt][r] = -sqrtf(fmaxf(s2, 0.f)) * lsm;
        }
        float m = fmaxf(fmaxf(logit[nt][0], logit[nt][1]),
                        fmaxf(logit[nt][2], logit[nt][3]));
        m = fmaxf(m, __shfl_xor(m, 16));
        m = fmaxf(m, __shfl_xor(m, 32));           // slab max, replicated
        if (quad == 0) wstat[w][nt * 16 + l15] = m;
    }
    __syncthreads();
    #pragma unroll
    for (int nt = 0; nt < 2; ++nt) {
        int dd = nt * 16 + l15;
        Mc[nt] = fmaxf(fmaxf(wstat[0][dd], wstat[1][dd]),
                       fmaxf(wstat[2][dd], wstat[3][dd]));
        float s = 0.f;
        #pragma unroll
        for (int r = 0; r < 4; ++r) {
            float e = expf(logit[nt][r] - Mc[nt]);
            eloc[nt][r] = e;
            s += e;
        }
        s += __shfl_xor(s, 16);
        s += __shfl_xor(s, 32);
        if (quad == 0) wsum[w][dd] = s;
    }
    __syncthreads();
    float* rec = ws + (size_t)((b * NDG + dg) * NCH + tc) * RECF;
    #pragma unroll
    for (int nt = 0; nt < 2; ++nt) {
        int dd = nt * 16 + l15;
        Sc[nt] = wsum[0][dd] + wsum[1][dd] + wsum[2][dd] + wsum[3][dd];
        #pragma unroll
        for (int r = 0; r < 4; ++r)                // es[d][t] bf16 (GEMM2 A layout)
            es[dd * ESS + w * 16 + quad * 4 + r] = f2bf(eloc[nt][r]);
    }
    if (w == 0 && quad == 0) {                     // chunk stats -> record
        rec[DG * Fn + l15]           = Mc[0];
        rec[DG * Fn + 16 + l15]      = Mc[1];
        rec[DG * Fn + DG + l15]      = Sc[0];
        rec[DG * Fn + DG + 16 + l15] = Sc[1];
    }
    __syncthreads();

    // ---- GEMM2: A[d][f] = sum_t e[t,d]*x_hi[t,f]; wave w owns f in [w*32, w*32+32) ----
    f32x4 acc2[2][2] = {{{0.f,0.f,0.f,0.f},{0.f,0.f,0.f,0.f}},
                        {{0.f,0.f,0.f,0.f},{0.f,0.f,0.f,0.f}}};
    const int f0w = w * 32;
    #pragma unroll
    for (int ks = 0; ks < 2; ++ks) {               // K = 64 t = 2 x 32
        short8 af[2];
        #pragma unroll
        for (int mt = 0; mt < 2; ++mt)
            af[mt] = *(const short8*)&es[(mt * 16 + l15) * ESS + ks * 32 + quad * 8];
        #pragma unroll
        for (int nt = 0; nt < 2; ++nt) {
            int ff = f0w + nt * 16 + l15;
            short8 bf = *(const short8*)&xsT[ff * XT + ks * 32 + quad * 8];
            #pragma unroll
            for (int mt = 0; mt < 2; ++mt)
                acc2[mt][nt] = __builtin_amdgcn_mfma_f32_16x16x32_bf16(af[mt], bf, acc2[mt][nt], 0, 0, 0);
        }
    }
    // epilogue: D layout n=l15 -> f, m=quad*4+r -> d
    #pragma unroll
    for (int mt = 0; mt < 2; ++mt)
        #pragma unroll
        for (int nt = 0; nt < 2; ++nt)
            #pragma unroll
            for (int r = 0; r < 4; ++r) {
                int dd = mt * 16 + quad * 4 + r;
                int ff = f0w + nt * 16 + l15;
                rec[dd * Fn + ff] = acc2[mt][nt][r];
            }
}

__global__ __launch_bounds__(128) void lde_combine(
    const float* __restrict__ ws, const float* __restrict__ dic,
    float* __restrict__ out)
{
    const int b = blockIdx.x & 7;
    const int d = blockIdx.x >> 3;
    const int dg = d >> 5, dl = d & 31;
    const int f = threadIdx.x;

    const float* base = ws + (size_t)((b * NDG + dg) * NCH) * RECF;
    float M = -INFINITY;
    #pragma unroll 4
    for (int c = 0; c < NCH; ++c)
        M = fmaxf(M, base[(size_t)c * RECF + DG * Fn + dl]);
    float A = 0.f, S = 0.f;
    #pragma unroll 4
    for (int c = 0; c < NCH; ++c) {
        const float* rec = base + (size_t)c * RECF;
        float sc = expf(rec[DG * Fn + dl] - M);
        S += rec[DG * Fn + DG + dl] * sc;
        A += rec[dl * Fn + f] * sc;
    }
    out[((size_t)b * Dn + d) * Fn + f] = (A - S * dic[d * Fn + f]) / S;
}

extern "C" void kernel_launch(void* const* d_in, const int* in_sizes, int n_in,
                              void* d_out, int out_size, void* d_ws, size_t ws_size,
                              hipStream_t stream) {
    const float* x   = (const float*)d_in[0];
    const float* dic = (const float*)d_in[1];
    const float* wei = (const float*)d_in[2];
    float* out = (float*)d_out;
    float* ws  = (float*)d_ws;   // needs Bn*NDG*NCH*RECF*4 = 8.52 MB

    hipLaunchKernelGGL(lde_mfma, dim3(Bn * NDG * NCH), dim3(256), 0, stream,
                       x, dic, wei, ws);
    hipLaunchKernelGGL(lde_combine, dim3(Bn * Dn), dim3(128), 0, stream,
                       ws, dic, out);
}